// Round 4
// baseline (7672.987 us; speedup 1.0000x reference)
//
#include <hip/hip_runtime.h>
#include <math.h>

#define B_   64
#define T_   366
#define IN_  24
#define H1_  1024
#define H2_  2048
#define HM_  2048
#define G3_  (3 * HM_)
#define PEN_ 1024
#define C_   21
#define BT_  (B_ * T_)

#define TC_  61              // T-chunk length (366 = 6*61)
#define NCH  6
#define MC   (B_ * TC_)      // 3904 rows per chunk

typedef unsigned short bf16_t;
typedef __bf16 bf16x8 __attribute__((ext_vector_type(8)));
typedef float  f32x4  __attribute__((ext_vector_type(4)));

__device__ __forceinline__ float bf2f(bf16_t u) {
  return __uint_as_float(((unsigned int)u) << 16);
}
__device__ __forceinline__ bf16_t f2bf(float f) {
  unsigned int x = __float_as_uint(f);
  unsigned int r = (x + 0x7fffu + ((x >> 16) & 1u)) >> 16;
  return (bf16_t)r;
}

struct ushort4_t { bf16_t x, y, z, w; };

#define AS1 __attribute__((address_space(1)))
#define AS3 __attribute__((address_space(3)))

// ---------------------------------------------------------------------------
// MFMA bf16 GEMM: C = act(A@W^T+b).  (R2-proven, unchanged)
//   WBF=1: W pre-converted bf16; m97-style global_load_lds (16B) staging into
//          linear [128][32] LDS — removes reg round-trip + address VALU.
//   WBF=0: fp32-W reg-staged path (R5-proven fallback), LDT=40 padded.
// ---------------------------------------------------------------------------
#define GBM 128
#define GBN 128
#define GBK 32
#define LDT 40

template<int WBF>
__global__ __launch_bounds__(256) void gemm_mfma(
    const bf16_t* __restrict__ A, const float* __restrict__ Wf,
    const bf16_t* __restrict__ Wb,
    const float* __restrict__ bias, bf16_t* __restrict__ C,
    int M, int N, int K, int relu)
{
  __shared__ bf16_t Asl[GBM * LDT];
  __shared__ bf16_t Wsl[GBN * LDT];
  const int tid  = threadIdx.x;
  const int m0   = blockIdx.x * GBM;
  const int n0   = blockIdx.y * GBN;
  const int wave = tid >> 6;
  const int lane = tid & 63;
  const int l16  = lane & 15;
  const int quad = lane >> 4;
  const int wm   = (wave & 1) * 64;
  const int wn   = (wave >> 1) * 64;

  f32x4 acc[4][4];
  #pragma unroll
  for (int i = 0; i < 4; ++i)
    #pragma unroll
    for (int j = 0; j < 4; ++j)
      acc[i][j] = (f32x4){0.f, 0.f, 0.f, 0.f};

  if (WBF) {
    const int r4 = lane >> 2;
    const int sg = (lane & 3) << 3;    // bf16 elems: 0,8,16,24
    for (int k0 = 0; k0 < K; k0 += GBK) {
      #pragma unroll
      for (int it = 0; it < 2; ++it) {
        const int row = wave * 32 + it * 16 + r4;
        const int ar  = (m0 + row < M) ? (m0 + row) : (M - 1);
        __builtin_amdgcn_global_load_lds(
            (const AS1 void*)(A + (size_t)ar * K + k0 + sg),
            (AS3 void*)&Asl[(wave * 2 + it) * 512], 16, 0, 0);
        __builtin_amdgcn_global_load_lds(
            (const AS1 void*)(Wb + (size_t)(n0 + row) * K + k0 + sg),
            (AS3 void*)&Wsl[(wave * 2 + it) * 512], 16, 0, 0);
      }
      __syncthreads();
      bf16x8 af[4], bfr[4];
      #pragma unroll
      for (int i = 0; i < 4; ++i)
        af[i] = *(const bf16x8*)&Asl[(wm + 16 * i + l16) * 32 + quad * 8];
      #pragma unroll
      for (int j = 0; j < 4; ++j)
        bfr[j] = *(const bf16x8*)&Wsl[(wn + 16 * j + l16) * 32 + quad * 8];
      #pragma unroll
      for (int i = 0; i < 4; ++i)
        #pragma unroll
        for (int j = 0; j < 4; ++j)
          acc[i][j] = __builtin_amdgcn_mfma_f32_16x16x32_bf16(af[i], bfr[j], acc[i][j], 0, 0, 0);
      __syncthreads();
    }
  } else {
    const int srow = tid >> 1;
    const int sseg = (tid & 1) << 4;
    const int arow = (m0 + srow < M) ? (m0 + srow) : (M - 1);
    for (int k0 = 0; k0 < K; k0 += GBK) {
      {
        const bf16_t* ga = A + (size_t)arow * K + k0 + sseg;
        const uint4 a0 = *(const uint4*)ga;
        const uint4 a1 = *(const uint4*)(ga + 8);
        *(uint4*)&Asl[srow * LDT + sseg]     = a0;
        *(uint4*)&Asl[srow * LDT + sseg + 8] = a1;
        const float* gw = Wf + (size_t)(n0 + srow) * K + k0 + sseg;
        const float4 w0 = *(const float4*)gw;
        const float4 w1 = *(const float4*)(gw + 4);
        const float4 w2 = *(const float4*)(gw + 8);
        const float4 w3 = *(const float4*)(gw + 12);
        ushort4_t p0 = {f2bf(w0.x), f2bf(w0.y), f2bf(w0.z), f2bf(w0.w)};
        ushort4_t p1 = {f2bf(w1.x), f2bf(w1.y), f2bf(w1.z), f2bf(w1.w)};
        ushort4_t p2 = {f2bf(w2.x), f2bf(w2.y), f2bf(w2.z), f2bf(w2.w)};
        ushort4_t p3 = {f2bf(w3.x), f2bf(w3.y), f2bf(w3.z), f2bf(w3.w)};
        *(ushort4_t*)&Wsl[srow * LDT + sseg]      = p0;
        *(ushort4_t*)&Wsl[srow * LDT + sseg + 4]  = p1;
        *(ushort4_t*)&Wsl[srow * LDT + sseg + 8]  = p2;
        *(ushort4_t*)&Wsl[srow * LDT + sseg + 12] = p3;
      }
      __syncthreads();
      bf16x8 af[4], bfr[4];
      #pragma unroll
      for (int i = 0; i < 4; ++i)
        af[i] = *(const bf16x8*)&Asl[(wm + 16 * i + l16) * LDT + quad * 8];
      #pragma unroll
      for (int j = 0; j < 4; ++j)
        bfr[j] = *(const bf16x8*)&Wsl[(wn + 16 * j + l16) * LDT + quad * 8];
      #pragma unroll
      for (int i = 0; i < 4; ++i)
        #pragma unroll
        for (int j = 0; j < 4; ++j)
          acc[i][j] = __builtin_amdgcn_mfma_f32_16x16x32_bf16(af[i], bfr[j], acc[i][j], 0, 0, 0);
      __syncthreads();
    }
  }

  #pragma unroll
  for (int j = 0; j < 4; ++j) {
    const int n = n0 + wn + 16 * j + l16;
    const float bn = bias[n];
    #pragma unroll
    for (int i = 0; i < 4; ++i) {
      #pragma unroll
      for (int reg = 0; reg < 4; ++reg) {
        const int m = m0 + wm + 16 * i + quad * 4 + reg;
        if (m < M) {
          float v = acc[i][j][reg] + bn;
          if (relu) v = fmaxf(v, 0.f);
          C[(size_t)m * N + n] = f2bf(v);
        }
      }
    }
  }
}

// ---------------------------------------------------------------------------
// GRU step v4 — LDS-FREE K-loop. 128 wgs x 512 thr (8 waves). Each wave owns
// a private K/8=256 slice and all 4 row-tiles (M=64): A and B MFMA fragments
// are loaded DIRECTLY from global (h and W_hh slabs are L2-resident; fragment
// addresses are base + compile-time offsets). No __syncthreads in the K-loop,
// no W redundancy (disjoint K-slices), 12 independent MFMA chains of depth 8
// per wave. One final 8-way reduce via LDS (conflict-free b128 pattern), then
// the R1-proven epilogue (identical thread mapping / gate math / writes).
// Fragment index formulas identical to the staged version (verified mapping).
// ---------------------------------------------------------------------------
__global__ __launch_bounds__(512) void gru_step(
    const bf16_t* __restrict__ h_bf_in, float* __restrict__ h_f,
    const bf16_t* __restrict__ Whh_bf, const bf16_t* __restrict__ xg_c,
    const float* __restrict__ b_hh,
    bf16_t* __restrict__ h_bf_out, bf16_t* __restrict__ hs_c, int tt)
{
  __shared__ float red[8][4][3][64][4];   // [wv][rt][g][lane][reg] = 98,304 B
  const int tid  = threadIdx.x;
  const int wv8  = tid >> 6;          // 0..7: wave id = K-slice id
  const int lane = tid & 63;
  const int l16  = lane & 15;
  const int quad = lane >> 4;
  const int wave = wv8 & 3;           // epilogue row-tile owner (tid<256)
  const int j0   = blockIdx.x * 16;
  const int j    = j0 + l16;
  const int kq   = wv8 * (HM_ / 8);   // this wave's K-slice base (256 wide)

  // fragment base pointers (identical index formulas to staged version)
  const bf16_t* pa0 = h_bf_in + (size_t)(0 * 16 + l16) * HM_ + kq + quad * 8;
  const bf16_t* pa1 = h_bf_in + (size_t)(1 * 16 + l16) * HM_ + kq + quad * 8;
  const bf16_t* pa2 = h_bf_in + (size_t)(2 * 16 + l16) * HM_ + kq + quad * 8;
  const bf16_t* pa3 = h_bf_in + (size_t)(3 * 16 + l16) * HM_ + kq + quad * 8;
  const bf16_t* pb0 = Whh_bf + (size_t)(0 * HM_ + j) * HM_ + kq + quad * 8;
  const bf16_t* pb1 = Whh_bf + (size_t)(1 * HM_ + j) * HM_ + kq + quad * 8;
  const bf16_t* pb2 = Whh_bf + (size_t)(2 * HM_ + j) * HM_ + kq + quad * 8;

  // epilogue operand prefetch (waves 0-3 only) — hides tail latency
  bf16_t xrb[4], xzb[4], xnb[4];
  float  hp[4];
  if (tid < 256) {
    #pragma unroll
    for (int reg = 0; reg < 4; ++reg) {
      const int b = wave * 16 + quad * 4 + reg;
      const size_t xrow = (size_t)(b * TC_ + tt) * G3_;
      xrb[reg] = xg_c[xrow + j];
      xzb[reg] = xg_c[xrow + HM_ + j];
      xnb[reg] = xg_c[xrow + 2 * HM_ + j];
      hp[reg]  = h_f[b * HM_ + j];
    }
  }

  f32x4 acc[4][3];
  #pragma unroll
  for (int rt = 0; rt < 4; ++rt)
    #pragma unroll
    for (int g = 0; g < 3; ++g)
      acc[rt][g] = (f32x4){0.f, 0.f, 0.f, 0.f};

  #pragma unroll
  for (int kt = 0; kt < 8; ++kt) {
    const int off = kt * 32;          // folds into global-load offset imm
    const bf16x8 a0 = *(const bf16x8*)(pa0 + off);
    const bf16x8 a1 = *(const bf16x8*)(pa1 + off);
    const bf16x8 a2 = *(const bf16x8*)(pa2 + off);
    const bf16x8 a3 = *(const bf16x8*)(pa3 + off);
    const bf16x8 b0 = *(const bf16x8*)(pb0 + off);
    const bf16x8 b1 = *(const bf16x8*)(pb1 + off);
    const bf16x8 b2 = *(const bf16x8*)(pb2 + off);
    acc[0][0] = __builtin_amdgcn_mfma_f32_16x16x32_bf16(a0, b0, acc[0][0], 0, 0, 0);
    acc[0][1] = __builtin_amdgcn_mfma_f32_16x16x32_bf16(a0, b1, acc[0][1], 0, 0, 0);
    acc[0][2] = __builtin_amdgcn_mfma_f32_16x16x32_bf16(a0, b2, acc[0][2], 0, 0, 0);
    acc[1][0] = __builtin_amdgcn_mfma_f32_16x16x32_bf16(a1, b0, acc[1][0], 0, 0, 0);
    acc[1][1] = __builtin_amdgcn_mfma_f32_16x16x32_bf16(a1, b1, acc[1][1], 0, 0, 0);
    acc[1][2] = __builtin_amdgcn_mfma_f32_16x16x32_bf16(a1, b2, acc[1][2], 0, 0, 0);
    acc[2][0] = __builtin_amdgcn_mfma_f32_16x16x32_bf16(a2, b0, acc[2][0], 0, 0, 0);
    acc[2][1] = __builtin_amdgcn_mfma_f32_16x16x32_bf16(a2, b1, acc[2][1], 0, 0, 0);
    acc[2][2] = __builtin_amdgcn_mfma_f32_16x16x32_bf16(a2, b2, acc[2][2], 0, 0, 0);
    acc[3][0] = __builtin_amdgcn_mfma_f32_16x16x32_bf16(a3, b0, acc[3][0], 0, 0, 0);
    acc[3][1] = __builtin_amdgcn_mfma_f32_16x16x32_bf16(a3, b1, acc[3][1], 0, 0, 0);
    acc[3][2] = __builtin_amdgcn_mfma_f32_16x16x32_bf16(a3, b2, acc[3][2], 0, 0, 0);
  }

  // 8-way reduce: all waves write partials (contiguous b128, conflict-free)
  #pragma unroll
  for (int rt = 0; rt < 4; ++rt)
    #pragma unroll
    for (int g = 0; g < 3; ++g)
      *(f32x4*)&red[wv8][rt][g][lane][0] = acc[rt][g];
  __syncthreads();
  if (tid >= 256) return;

  f32x4 s0 = (f32x4){0.f, 0.f, 0.f, 0.f};
  f32x4 s1 = s0, s2 = s0;
  #pragma unroll
  for (int wv = 0; wv < 8; ++wv) {
    s0 += *(const f32x4*)&red[wv][wave][0][lane][0];
    s1 += *(const f32x4*)&red[wv][wave][1][lane][0];
    s2 += *(const f32x4*)&red[wv][wave][2][lane][0];
  }

  // epilogue — R1-proven gate math, operands already in registers
  const float bh_r = b_hh[j];
  const float bh_z = b_hh[HM_ + j];
  const float bh_n = b_hh[2 * HM_ + j];
  #pragma unroll
  for (int reg = 0; reg < 4; ++reg) {
    const int b = wave * 16 + quad * 4 + reg;
    const float xr = bf2f(xrb[reg]);
    const float xz = bf2f(xzb[reg]);
    const float xn = bf2f(xnb[reg]);
    const float r = 1.f / (1.f + expf(-(xr + s0[reg] + bh_r)));
    const float z = 1.f / (1.f + expf(-(xz + s1[reg] + bh_z)));
    const float n = tanhf(xn + r * (s2[reg] + bh_n));
    const float hnew = (1.f - z) * n + z * hp[reg];
    h_f[b * HM_ + j] = hnew;
    const bf16_t hb = f2bf(hnew);
    h_bf_out[b * HM_ + j] = hb;
    hs_c[(size_t)(b * TC_ + tt) * HM_ + j] = hb;
  }
}

// ---------------------------------------------------------------------------
// L1 GEMM with gathered rows (K=24, fp32 vector), bf16 output. (R5-proven)
// ---------------------------------------------------------------------------
#define BM 64
#define BN 64
#define BKK 16

__global__ __launch_bounds__(256) void gemm_l1_gather(
    const float* __restrict__ x, const float* __restrict__ W,
    const float* __restrict__ bias, bf16_t* __restrict__ C, int t0)
{
  __shared__ float As[BKK][BM];
  __shared__ float Ws[BKK][BN];
  const int tid = threadIdx.x;
  const int m0 = blockIdx.x * BM;
  const int n0 = blockIdx.y * BN;
  const int lr = tid >> 2;
  const int kq = (tid & 3) << 2;
  const int ty = tid >> 4;
  const int tx = tid & 15;
  const int r = m0 + lr;
  const int b = r / TC_;
  const int tt = r - b * TC_;
  const size_t srow = (size_t)b * T_ + t0 + tt;
  float acc[4][4] = {};
  for (int k0 = 0; k0 < IN_; k0 += BKK) {
    {
      float v0 = 0.f, v1 = 0.f, v2 = 0.f, v3 = 0.f;
      const int kk = k0 + kq;
      const float* src = x + srow * IN_ + kk;
      if (kk + 4 <= IN_) {
        const float4 v = *(const float4*)src;
        v0 = v.x; v1 = v.y; v2 = v.z; v3 = v.w;
      }
      As[kq + 0][lr] = v0; As[kq + 1][lr] = v1;
      As[kq + 2][lr] = v2; As[kq + 3][lr] = v3;
      float w0 = 0.f, w1 = 0.f, w2 = 0.f, w3 = 0.f;
      const float* srcw = W + (size_t)(n0 + lr) * IN_ + kk;
      if (kk + 4 <= IN_) {
        const float4 w = *(const float4*)srcw;
        w0 = w.x; w1 = w.y; w2 = w.z; w3 = w.w;
      }
      Ws[kq + 0][lr] = w0; Ws[kq + 1][lr] = w1;
      Ws[kq + 2][lr] = w2; Ws[kq + 3][lr] = w3;
    }
    __syncthreads();
    #pragma unroll
    for (int k = 0; k < BKK; ++k) {
      const float4 av = *(const float4*)&As[k][ty << 2];
      const float4 bv = *(const float4*)&Ws[k][tx << 2];
      const float aa[4] = {av.x, av.y, av.z, av.w};
      const float bb[4] = {bv.x, bv.y, bv.z, bv.w};
      #pragma unroll
      for (int i = 0; i < 4; ++i)
        #pragma unroll
        for (int j = 0; j < 4; ++j)
          acc[i][j] = fmaf(aa[i], bb[j], acc[i][j]);
    }
    __syncthreads();
  }
  const float4 bvec = *(const float4*)&bias[n0 + (tx << 2)];
  const float bb[4] = {bvec.x, bvec.y, bvec.z, bvec.w};
  #pragma unroll
  for (int i = 0; i < 4; ++i) {
    ushort4_t ov;
    ov.x = f2bf(fmaxf(acc[i][0] + bb[0], 0.f));
    ov.y = f2bf(fmaxf(acc[i][1] + bb[1], 0.f));
    ov.z = f2bf(fmaxf(acc[i][2] + bb[2], 0.f));
    ov.w = f2bf(fmaxf(acc[i][3] + bb[3], 0.f));
    *(ushort4_t*)&C[(size_t)(m0 + (ty << 2) + i) * H1_ + n0 + (tx << 2)] = ov;
  }
}

// Heads for one chunk (outs bf16). (R5-proven)
__global__ __launch_bounds__(256) void heads_kernel(
    const bf16_t* __restrict__ outs_c, const int* __restrict__ label,
    const float* __restrict__ W4, const float* __restrict__ b4,
    const float* __restrict__ W5, const float* __restrict__ b5,
    const float* __restrict__ W6, const float* __restrict__ b6,
    float* __restrict__ out, int t0)
{
  const int r = blockIdx.x;
  const int b = r / TC_;
  const int tt = r - b * TC_;
  int lab = label[b];
  lab = lab < 0 ? 0 : (lab > C_ - 1 ? C_ - 1 : lab);
  const int tid = threadIdx.x;
  const bf16_t* o = outs_c + (size_t)r * PEN_;
  const float* w4 = W4 + (size_t)lab * PEN_;
  const float* w5 = W5 + (size_t)lab * PEN_;
  const float* w6 = W6 + (size_t)lab * PEN_;
  float s4 = 0.f, s5 = 0.f, s6 = 0.f;
  for (int p = tid; p < PEN_; p += 256) {
    const float ov = bf2f(o[p]);
    s4 = fmaf(ov, w4[p], s4);
    s5 = fmaf(ov, w5[p], s5);
    s6 = fmaf(ov, w6[p], s6);
  }
  #pragma unroll
  for (int off = 32; off > 0; off >>= 1) {
    s4 += __shfl_down(s4, off, 64);
    s5 += __shfl_down(s5, off, 64);
    s6 += __shfl_down(s6, off, 64);
  }
  __shared__ float red[4][3];
  const int wave = tid >> 6;
  if ((tid & 63) == 0) { red[wave][0] = s4; red[wave][1] = s5; red[wave][2] = s6; }
  __syncthreads();
  if (tid == 0) {
    const int bt = b * T_ + t0 + tt;
    out[bt]           = red[0][0] + red[1][0] + red[2][0] + red[3][0] + b4[lab];
    out[BT_ + bt]     = red[0][1] + red[1][1] + red[2][1] + red[3][1] + b5[lab];
    out[2 * BT_ + bt] = red[0][2] + red[1][2] + red[2][2] + red[3][2] + b6[lab];
    if (t0 == 0 && r == 0) { out[3 * BT_] = 0.f; out[3 * BT_ + 1] = 0.f; }
  }
}

__global__ __launch_bounds__(256) void cvt_bf(const float* __restrict__ src,
                                              bf16_t* __restrict__ dst, int n) {
  const int i = (blockIdx.x * 256 + threadIdx.x) * 4;
  if (i + 4 <= n) {
    const float4 v = *(const float4*)&src[i];
    ushort4_t o = {f2bf(v.x), f2bf(v.y), f2bf(v.z), f2bf(v.w)};
    *(ushort4_t*)&dst[i] = o;
  }
}

__global__ __launch_bounds__(256) void zero_h(float* __restrict__ hf,
                                              bf16_t* __restrict__ hb0,
                                              bf16_t* __restrict__ hb1) {
  const int i = blockIdx.x * 256 + threadIdx.x;  // 131072
  hf[i] = 0.f; hb0[i] = 0; hb1[i] = 0;
}

extern "C" void kernel_launch(void* const* d_in, const int* in_sizes, int n_in,
                              void* d_out, int out_size, void* d_ws, size_t ws_size,
                              hipStream_t stream) {
  const float* x     = (const float*)d_in[0];
  const int*   label = (const int*)d_in[1];
  const float* W1    = (const float*)d_in[2];
  const float* b1    = (const float*)d_in[3];
  const float* W2    = (const float*)d_in[4];
  const float* b2    = (const float*)d_in[5];
  const float* W_ih  = (const float*)d_in[6];
  const float* W_hh  = (const float*)d_in[7];
  const float* b_ih  = (const float*)d_in[8];
  const float* b_hh  = (const float*)d_in[9];
  const float* W3    = (const float*)d_in[10];
  const float* b3    = (const float*)d_in[11];
  const float* W4    = (const float*)d_in[12];
  const float* b4    = (const float*)d_in[13];
  const float* W5    = (const float*)d_in[14];
  const float* b5    = (const float*)d_in[15];
  const float* W6    = (const float*)d_in[16];
  const float* b6    = (const float*)d_in[17];

  // Workspace layout (bytes). Base = 98,172,928 (R4-R7 proven).
  // bf16-weight extension (+33,554,432) used only if ws_size permits.
  const size_t NEEDED  = 98172928UL;
  const size_t NEEDED2 = 131727360UL;
  if (ws_size < NEEDED) return;
  const int use_bf = (ws_size >= NEEDED2);

  char* ws = (char*)d_ws;
  bf16_t* xg_c   = (bf16_t*)(ws + 0);
  bf16_t* out2_c = (bf16_t*)(ws + 47972352UL);
  bf16_t* hs_c   = out2_c;
  bf16_t* out1_c = (bf16_t*)(ws + 63963136UL);
  bf16_t* outs_c = out1_c;
  bf16_t* Whh_bf = (bf16_t*)(ws + 71958528UL);
  float*  h_f    = (float*)(ws + 97124352UL);
  bf16_t* hbuf[2];
  hbuf[0] = (bf16_t*)(ws + 97648640UL);
  hbuf[1] = (bf16_t*)(ws + 97910784UL);
  bf16_t* W2b  = (bf16_t*)(ws + 98172928UL);   // 4,194,304 B
  bf16_t* Wihb = (bf16_t*)(ws + 102367232UL);  // 25,165,824 B
  bf16_t* W3b  = (bf16_t*)(ws + 127533056UL);  // 4,194,304 B
  float* out = (float*)d_out;

  const dim3 blk(256);

  cvt_bf<<<dim3(G3_ * HM_ / 1024), blk, 0, stream>>>(W_hh, Whh_bf, G3_ * HM_);
  zero_h<<<dim3(B_ * HM_ / 256), blk, 0, stream>>>(h_f, hbuf[0], hbuf[1]);
  if (use_bf) {
    cvt_bf<<<dim3(H2_ * H1_ / 1024), blk, 0, stream>>>(W2, W2b, H2_ * H1_);
    cvt_bf<<<dim3(G3_ * H2_ / 1024), blk, 0, stream>>>(W_ih, Wihb, G3_ * H2_);
    cvt_bf<<<dim3(PEN_ * HM_ / 1024), blk, 0, stream>>>(W3, W3b, PEN_ * HM_);
  }

  int pp = 0;
  for (int c = 0; c < NCH; ++c) {
    const int t0 = c * TC_;
    gemm_l1_gather<<<dim3(MC / BM, H1_ / BN), blk, 0, stream>>>(x, W1, b1, out1_c, t0);
    if (use_bf) {
      gemm_mfma<1><<<dim3((MC + GBM - 1) / GBM, H2_ / GBN), blk, 0, stream>>>(
          out1_c, nullptr, W2b, b2, out2_c, MC, H2_, H1_, 1);
      gemm_mfma<1><<<dim3((MC + GBM - 1) / GBM, G3_ / GBN), blk, 0, stream>>>(
          out2_c, nullptr, Wihb, b_ih, xg_c, MC, G3_, H2_, 0);
    } else {
      gemm_mfma<0><<<dim3((MC + GBM - 1) / GBM, H2_ / GBN), blk, 0, stream>>>(
          out1_c, W2, nullptr, b2, out2_c, MC, H2_, H1_, 1);
      gemm_mfma<0><<<dim3((MC + GBM - 1) / GBM, G3_ / GBN), blk, 0, stream>>>(
          out2_c, W_ih, nullptr, b_ih, xg_c, MC, G3_, H2_, 0);
    }

    for (int tt = 0; tt < TC_; ++tt) {
      gru_step<<<dim3(HM_ / 16), dim3(512), 0, stream>>>(
          hbuf[pp], h_f, Whh_bf, xg_c, b_hh, hbuf[1 - pp], hs_c, tt);
      pp ^= 1;
    }

    if (use_bf) {
      gemm_mfma<1><<<dim3((MC + GBM - 1) / GBM, PEN_ / GBN), blk, 0, stream>>>(
          hs_c, nullptr, W3b, b3, outs_c, MC, PEN_, HM_, 1);
    } else {
      gemm_mfma<0><<<dim3((MC + GBM - 1) / GBM, PEN_ / GBN), blk, 0, stream>>>(
          hs_c, W3, nullptr, b3, outs_c, MC, PEN_, HM_, 1);
    }
    heads_kernel<<<dim3(MC), blk, 0, stream>>>(
        outs_c, label, W4, b4, W5, b5, W6, b6, out, t0);
  }
}

// Round 5
// 7075.129 us; speedup vs baseline: 1.0845x; 1.0845x over previous
//
#include <hip/hip_runtime.h>
#include <math.h>

#define B_   64
#define T_   366
#define IN_  24
#define H1_  1024
#define H2_  2048
#define HM_  2048
#define G3_  (3 * HM_)
#define PEN_ 1024
#define C_   21
#define BT_  (B_ * T_)

#define TC_  61              // T-chunk length (366 = 6*61)
#define NCH  6
#define MC   (B_ * TC_)      // 3904 rows per chunk

typedef unsigned short bf16_t;
typedef __bf16 bf16x8 __attribute__((ext_vector_type(8)));
typedef float  f32x4  __attribute__((ext_vector_type(4)));

__device__ __forceinline__ float bf2f(bf16_t u) {
  return __uint_as_float(((unsigned int)u) << 16);
}
__device__ __forceinline__ bf16_t f2bf(float f) {
  unsigned int x = __float_as_uint(f);
  unsigned int r = (x + 0x7fffu + ((x >> 16) & 1u)) >> 16;
  return (bf16_t)r;
}

struct ushort4_t { bf16_t x, y, z, w; };

#define AS1 __attribute__((address_space(1)))
#define AS3 __attribute__((address_space(3)))

// ---------------------------------------------------------------------------
// MFMA bf16 GEMM: C = act(A@W^T+b).  (R2-proven, unchanged)
//   WBF=1: W pre-converted bf16; m97-style global_load_lds (16B) staging into
//          linear [128][32] LDS — removes reg round-trip + address VALU.
//   WBF=0: fp32-W reg-staged path (R5-proven fallback), LDT=40 padded.
// ---------------------------------------------------------------------------
#define GBM 128
#define GBN 128
#define GBK 32
#define LDT 40

template<int WBF>
__global__ __launch_bounds__(256) void gemm_mfma(
    const bf16_t* __restrict__ A, const float* __restrict__ Wf,
    const bf16_t* __restrict__ Wb,
    const float* __restrict__ bias, bf16_t* __restrict__ C,
    int M, int N, int K, int relu)
{
  __shared__ bf16_t Asl[GBM * LDT];
  __shared__ bf16_t Wsl[GBN * LDT];
  const int tid  = threadIdx.x;
  const int m0   = blockIdx.x * GBM;
  const int n0   = blockIdx.y * GBN;
  const int wave = tid >> 6;
  const int lane = tid & 63;
  const int l16  = lane & 15;
  const int quad = lane >> 4;
  const int wm   = (wave & 1) * 64;
  const int wn   = (wave >> 1) * 64;

  f32x4 acc[4][4];
  #pragma unroll
  for (int i = 0; i < 4; ++i)
    #pragma unroll
    for (int j = 0; j < 4; ++j)
      acc[i][j] = (f32x4){0.f, 0.f, 0.f, 0.f};

  if (WBF) {
    const int r4 = lane >> 2;
    const int sg = (lane & 3) << 3;    // bf16 elems: 0,8,16,24
    for (int k0 = 0; k0 < K; k0 += GBK) {
      #pragma unroll
      for (int it = 0; it < 2; ++it) {
        const int row = wave * 32 + it * 16 + r4;
        const int ar  = (m0 + row < M) ? (m0 + row) : (M - 1);
        __builtin_amdgcn_global_load_lds(
            (const AS1 void*)(A + (size_t)ar * K + k0 + sg),
            (AS3 void*)&Asl[(wave * 2 + it) * 512], 16, 0, 0);
        __builtin_amdgcn_global_load_lds(
            (const AS1 void*)(Wb + (size_t)(n0 + row) * K + k0 + sg),
            (AS3 void*)&Wsl[(wave * 2 + it) * 512], 16, 0, 0);
      }
      __syncthreads();
      bf16x8 af[4], bfr[4];
      #pragma unroll
      for (int i = 0; i < 4; ++i)
        af[i] = *(const bf16x8*)&Asl[(wm + 16 * i + l16) * 32 + quad * 8];
      #pragma unroll
      for (int j = 0; j < 4; ++j)
        bfr[j] = *(const bf16x8*)&Wsl[(wn + 16 * j + l16) * 32 + quad * 8];
      #pragma unroll
      for (int i = 0; i < 4; ++i)
        #pragma unroll
        for (int j = 0; j < 4; ++j)
          acc[i][j] = __builtin_amdgcn_mfma_f32_16x16x32_bf16(af[i], bfr[j], acc[i][j], 0, 0, 0);
      __syncthreads();
    }
  } else {
    const int srow = tid >> 1;
    const int sseg = (tid & 1) << 4;
    const int arow = (m0 + srow < M) ? (m0 + srow) : (M - 1);
    for (int k0 = 0; k0 < K; k0 += GBK) {
      {
        const bf16_t* ga = A + (size_t)arow * K + k0 + sseg;
        const uint4 a0 = *(const uint4*)ga;
        const uint4 a1 = *(const uint4*)(ga + 8);
        *(uint4*)&Asl[srow * LDT + sseg]     = a0;
        *(uint4*)&Asl[srow * LDT + sseg + 8] = a1;
        const float* gw = Wf + (size_t)(n0 + srow) * K + k0 + sseg;
        const float4 w0 = *(const float4*)gw;
        const float4 w1 = *(const float4*)(gw + 4);
        const float4 w2 = *(const float4*)(gw + 8);
        const float4 w3 = *(const float4*)(gw + 12);
        ushort4_t p0 = {f2bf(w0.x), f2bf(w0.y), f2bf(w0.z), f2bf(w0.w)};
        ushort4_t p1 = {f2bf(w1.x), f2bf(w1.y), f2bf(w1.z), f2bf(w1.w)};
        ushort4_t p2 = {f2bf(w2.x), f2bf(w2.y), f2bf(w2.z), f2bf(w2.w)};
        ushort4_t p3 = {f2bf(w3.x), f2bf(w3.y), f2bf(w3.z), f2bf(w3.w)};
        *(ushort4_t*)&Wsl[srow * LDT + sseg]      = p0;
        *(ushort4_t*)&Wsl[srow * LDT + sseg + 4]  = p1;
        *(ushort4_t*)&Wsl[srow * LDT + sseg + 8]  = p2;
        *(ushort4_t*)&Wsl[srow * LDT + sseg + 12] = p3;
      }
      __syncthreads();
      bf16x8 af[4], bfr[4];
      #pragma unroll
      for (int i = 0; i < 4; ++i)
        af[i] = *(const bf16x8*)&Asl[(wm + 16 * i + l16) * LDT + quad * 8];
      #pragma unroll
      for (int j = 0; j < 4; ++j)
        bfr[j] = *(const bf16x8*)&Wsl[(wn + 16 * j + l16) * LDT + quad * 8];
      #pragma unroll
      for (int i = 0; i < 4; ++i)
        #pragma unroll
        for (int j = 0; j < 4; ++j)
          acc[i][j] = __builtin_amdgcn_mfma_f32_16x16x32_bf16(af[i], bfr[j], acc[i][j], 0, 0, 0);
      __syncthreads();
    }
  }

  #pragma unroll
  for (int j = 0; j < 4; ++j) {
    const int n = n0 + wn + 16 * j + l16;
    const float bn = bias[n];
    #pragma unroll
    for (int i = 0; i < 4; ++i) {
      #pragma unroll
      for (int reg = 0; reg < 4; ++reg) {
        const int m = m0 + wm + 16 * i + quad * 4 + reg;
        if (m < M) {
          float v = acc[i][j][reg] + bn;
          if (relu) v = fmaxf(v, 0.f);
          C[(size_t)m * N + n] = f2bf(v);
        }
      }
    }
  }
}

// ---------------------------------------------------------------------------
// GRU step v5 — proven staged structure (coalesced reg->LDS staging, 2
// barriers/phase, proven epilogue) generalized from 2 to 4 K-teams:
// 128 wgs x 512 thr; team t (128 thr, 2 waves) owns K-slice [t*512,(t+1)*512)
// -> 8 serial phases instead of 16 (the measured cost driver). Each wave
// computes 2 row-tiles x 3 gates. 4-way cross-team reduce via conflict-free
// b128 LDS pattern, then the R1-proven epilogue verbatim.
// ---------------------------------------------------------------------------
#define HLD 72   // padded LDS stride for 64-k tiles

__global__ __launch_bounds__(512) void gru_step(
    const bf16_t* __restrict__ h_bf_in, float* __restrict__ h_f,
    const bf16_t* __restrict__ Whh_bf, const bf16_t* __restrict__ xg_c,
    const float* __restrict__ b_hh,
    bf16_t* __restrict__ h_bf_out, bf16_t* __restrict__ hs_c, int tt)
{
  // hst: 4 teams x 64 rows x HLD = 36,864 B ; wst: 4 x 48 x HLD = 27,648 B
  // red overlay (after K-loop): 4 teams x 4 rt x 3 g x 64 lanes x 4 = 49,152 B
  __shared__ char smem[66048];
  bf16_t* hst = (bf16_t*)smem;              // [team][64*HLD]
  bf16_t* wst = (bf16_t*)(smem + 36864);    // [team][48*HLD]
  float*  red = (float*)smem;               // overlay

  const int tid   = threadIdx.x;
  const int team  = tid >> 7;          // 0..3 (K-slice)
  const int ttid  = tid & 127;
  const int wavet = (tid >> 6) & 1;    // wave within team
  const int lane  = tid & 63;
  const int l16   = lane & 15;
  const int quad  = lane >> 4;
  const int j0    = blockIdx.x * 16;
  const int j     = j0 + l16;
  const int kbase = team * (HM_ / 4);  // 512-wide slice

  f32x4 acc[2][3];
  #pragma unroll
  for (int rt = 0; rt < 2; ++rt)
    #pragma unroll
    for (int g = 0; g < 3; ++g)
      acc[rt][g] = (f32x4){0.f, 0.f, 0.f, 0.f};

  // staging mapping (per team, 128 threads): 2 thr/row, 64 B each
  const int hrow = ttid >> 1;          // 0..63
  const int hseg = (ttid & 1) << 5;    // 0 or 32 elems
  const int wrow = ttid >> 1;          // 0..47 valid for ttid<96
  const int wg   = wrow >> 4;          // gate
  const int wjr  = wrow & 15;

  const bf16_t* gh_base = h_bf_in + (size_t)hrow * HM_ + kbase + hseg;
  const bf16_t* gw_base = Whh_bf + (size_t)(wg * HM_ + j0 + wjr) * HM_ + kbase + hseg;

  // epilogue operand prefetch (tid<256) — hides tail latency (R1-proven)
  bf16_t xrb[4], xzb[4], xnb[4];
  float  hp[4];
  const int ewave = tid >> 6;          // 0..3 valid for tid<256
  if (tid < 256) {
    #pragma unroll
    for (int reg = 0; reg < 4; ++reg) {
      const int b = ewave * 16 + quad * 4 + reg;
      const size_t xrow = (size_t)(b * TC_ + tt) * G3_;
      xrb[reg] = xg_c[xrow + j];
      xzb[reg] = xg_c[xrow + HM_ + j];
      xnb[reg] = xg_c[xrow + 2 * HM_ + j];
      hp[reg]  = h_f[b * HM_ + j];
    }
  }

  // preload k-tile 0 into registers (4 x uint4 = 64 B per thread)
  uint4 h0 = *(const uint4*)(gh_base);
  uint4 h1 = *(const uint4*)(gh_base + 8);
  uint4 h2 = *(const uint4*)(gh_base + 16);
  uint4 h3 = *(const uint4*)(gh_base + 24);
  uint4 w0 = {0u,0u,0u,0u}, w1 = w0, w2 = w0, w3 = w0;
  if (ttid < 96) {
    w0 = *(const uint4*)(gw_base);
    w1 = *(const uint4*)(gw_base + 8);
    w2 = *(const uint4*)(gw_base + 16);
    w3 = *(const uint4*)(gw_base + 24);
  }

  bf16_t* hT = hst + team * (64 * HLD);
  bf16_t* wT = wst + team * (48 * HLD);

  for (int k0 = 0; k0 < HM_ / 4; k0 += 64) {
    // regs -> LDS (team-private tile)
    *(uint4*)&hT[hrow * HLD + hseg]      = h0;
    *(uint4*)&hT[hrow * HLD + hseg + 8]  = h1;
    *(uint4*)&hT[hrow * HLD + hseg + 16] = h2;
    *(uint4*)&hT[hrow * HLD + hseg + 24] = h3;
    if (ttid < 96) {
      *(uint4*)&wT[wrow * HLD + hseg]      = w0;
      *(uint4*)&wT[wrow * HLD + hseg + 8]  = w1;
      *(uint4*)&wT[wrow * HLD + hseg + 16] = w2;
      *(uint4*)&wT[wrow * HLD + hseg + 24] = w3;
    }
    __syncthreads();
    // prefetch next k-tile (latency overlaps MFMA below)
    if (k0 + 64 < HM_ / 4) {
      h0 = *(const uint4*)(gh_base + k0 + 64);
      h1 = *(const uint4*)(gh_base + k0 + 64 + 8);
      h2 = *(const uint4*)(gh_base + k0 + 64 + 16);
      h3 = *(const uint4*)(gh_base + k0 + 64 + 24);
      if (ttid < 96) {
        w0 = *(const uint4*)(gw_base + k0 + 64);
        w1 = *(const uint4*)(gw_base + k0 + 64 + 8);
        w2 = *(const uint4*)(gw_base + k0 + 64 + 16);
        w3 = *(const uint4*)(gw_base + k0 + 64 + 24);
      }
    }
    #pragma unroll
    for (int s = 0; s < 2; ++s) {
      bf16x8 afr[2];
      #pragma unroll
      for (int rt = 0; rt < 2; ++rt)
        afr[rt] = *(const bf16x8*)&hT[((wavet * 2 + rt) * 16 + l16) * HLD + s * 32 + quad * 8];
      #pragma unroll
      for (int g = 0; g < 3; ++g) {
        const bf16x8 bfr = *(const bf16x8*)&wT[(g * 16 + l16) * HLD + s * 32 + quad * 8];
        acc[0][g] = __builtin_amdgcn_mfma_f32_16x16x32_bf16(afr[0], bfr, acc[0][g], 0, 0, 0);
        acc[1][g] = __builtin_amdgcn_mfma_f32_16x16x32_bf16(afr[1], bfr, acc[1][g], 0, 0, 0);
      }
    }
    __syncthreads();
  }

  // 4-way cross-team reduce (conflict-free b128: lane-contiguous blocks)
  #pragma unroll
  for (int rt = 0; rt < 2; ++rt) {
    const int rtg = wavet * 2 + rt;
    #pragma unroll
    for (int g = 0; g < 3; ++g)
      *(f32x4*)&red[(((team * 4 + rtg) * 3 + g) << 8) + (lane << 2)] = acc[rt][g];
  }
  __syncthreads();
  if (tid >= 256) return;

  f32x4 s0 = (f32x4){0.f, 0.f, 0.f, 0.f};
  f32x4 s1 = s0, s2 = s0;
  #pragma unroll
  for (int t = 0; t < 4; ++t) {
    s0 += *(const f32x4*)&red[(((t * 4 + ewave) * 3 + 0) << 8) + (lane << 2)];
    s1 += *(const f32x4*)&red[(((t * 4 + ewave) * 3 + 1) << 8) + (lane << 2)];
    s2 += *(const f32x4*)&red[(((t * 4 + ewave) * 3 + 2) << 8) + (lane << 2)];
  }

  // epilogue — R1-proven gate math, operands already in registers
  const float bh_r = b_hh[j];
  const float bh_z = b_hh[HM_ + j];
  const float bh_n = b_hh[2 * HM_ + j];
  #pragma unroll
  for (int reg = 0; reg < 4; ++reg) {
    const int b = ewave * 16 + quad * 4 + reg;
    const float xr = bf2f(xrb[reg]);
    const float xz = bf2f(xzb[reg]);
    const float xn = bf2f(xnb[reg]);
    const float r = 1.f / (1.f + expf(-(xr + s0[reg] + bh_r)));
    const float z = 1.f / (1.f + expf(-(xz + s1[reg] + bh_z)));
    const float n = tanhf(xn + r * (s2[reg] + bh_n));
    const float hnew = (1.f - z) * n + z * hp[reg];
    h_f[b * HM_ + j] = hnew;
    const bf16_t hb = f2bf(hnew);
    h_bf_out[b * HM_ + j] = hb;
    hs_c[(size_t)(b * TC_ + tt) * HM_ + j] = hb;
  }
}

// ---------------------------------------------------------------------------
// L1 GEMM with gathered rows (K=24, fp32 vector), bf16 output. (R5-proven)
// ---------------------------------------------------------------------------
#define BM 64
#define BN 64
#define BKK 16

__global__ __launch_bounds__(256) void gemm_l1_gather(
    const float* __restrict__ x, const float* __restrict__ W,
    const float* __restrict__ bias, bf16_t* __restrict__ C, int t0)
{
  __shared__ float As[BKK][BM];
  __shared__ float Ws[BKK][BN];
  const int tid = threadIdx.x;
  const int m0 = blockIdx.x * BM;
  const int n0 = blockIdx.y * BN;
  const int lr = tid >> 2;
  const int kq = (tid & 3) << 2;
  const int ty = tid >> 4;
  const int tx = tid & 15;
  const int r = m0 + lr;
  const int b = r / TC_;
  const int tt = r - b * TC_;
  const size_t srow = (size_t)b * T_ + t0 + tt;
  float acc[4][4] = {};
  for (int k0 = 0; k0 < IN_; k0 += BKK) {
    {
      float v0 = 0.f, v1 = 0.f, v2 = 0.f, v3 = 0.f;
      const int kk = k0 + kq;
      const float* src = x + srow * IN_ + kk;
      if (kk + 4 <= IN_) {
        const float4 v = *(const float4*)src;
        v0 = v.x; v1 = v.y; v2 = v.z; v3 = v.w;
      }
      As[kq + 0][lr] = v0; As[kq + 1][lr] = v1;
      As[kq + 2][lr] = v2; As[kq + 3][lr] = v3;
      float w0 = 0.f, w1 = 0.f, w2 = 0.f, w3 = 0.f;
      const float* srcw = W + (size_t)(n0 + lr) * IN_ + kk;
      if (kk + 4 <= IN_) {
        const float4 w = *(const float4*)srcw;
        w0 = w.x; w1 = w.y; w2 = w.z; w3 = w.w;
      }
      Ws[kq + 0][lr] = w0; Ws[kq + 1][lr] = w1;
      Ws[kq + 2][lr] = w2; Ws[kq + 3][lr] = w3;
    }
    __syncthreads();
    #pragma unroll
    for (int k = 0; k < BKK; ++k) {
      const float4 av = *(const float4*)&As[k][ty << 2];
      const float4 bv = *(const float4*)&Ws[k][tx << 2];
      const float aa[4] = {av.x, av.y, av.z, av.w};
      const float bb[4] = {bv.x, bv.y, bv.z, bv.w};
      #pragma unroll
      for (int i = 0; i < 4; ++i)
        #pragma unroll
        for (int j = 0; j < 4; ++j)
          acc[i][j] = fmaf(aa[i], bb[j], acc[i][j]);
    }
    __syncthreads();
  }
  const float4 bvec = *(const float4*)&bias[n0 + (tx << 2)];
  const float bb[4] = {bvec.x, bvec.y, bvec.z, bvec.w};
  #pragma unroll
  for (int i = 0; i < 4; ++i) {
    ushort4_t ov;
    ov.x = f2bf(fmaxf(acc[i][0] + bb[0], 0.f));
    ov.y = f2bf(fmaxf(acc[i][1] + bb[1], 0.f));
    ov.z = f2bf(fmaxf(acc[i][2] + bb[2], 0.f));
    ov.w = f2bf(fmaxf(acc[i][3] + bb[3], 0.f));
    *(ushort4_t*)&C[(size_t)(m0 + (ty << 2) + i) * H1_ + n0 + (tx << 2)] = ov;
  }
}

// Heads for one chunk (outs bf16). (R5-proven)
__global__ __launch_bounds__(256) void heads_kernel(
    const bf16_t* __restrict__ outs_c, const int* __restrict__ label,
    const float* __restrict__ W4, const float* __restrict__ b4,
    const float* __restrict__ W5, const float* __restrict__ b5,
    const float* __restrict__ W6, const float* __restrict__ b6,
    float* __restrict__ out, int t0)
{
  const int r = blockIdx.x;
  const int b = r / TC_;
  const int tt = r - b * TC_;
  int lab = label[b];
  lab = lab < 0 ? 0 : (lab > C_ - 1 ? C_ - 1 : lab);
  const int tid = threadIdx.x;
  const bf16_t* o = outs_c + (size_t)r * PEN_;
  const float* w4 = W4 + (size_t)lab * PEN_;
  const float* w5 = W5 + (size_t)lab * PEN_;
  const float* w6 = W6 + (size_t)lab * PEN_;
  float s4 = 0.f, s5 = 0.f, s6 = 0.f;
  for (int p = tid; p < PEN_; p += 256) {
    const float ov = bf2f(o[p]);
    s4 = fmaf(ov, w4[p], s4);
    s5 = fmaf(ov, w5[p], s5);
    s6 = fmaf(ov, w6[p], s6);
  }
  #pragma unroll
  for (int off = 32; off > 0; off >>= 1) {
    s4 += __shfl_down(s4, off, 64);
    s5 += __shfl_down(s5, off, 64);
    s6 += __shfl_down(s6, off, 64);
  }
  __shared__ float red[4][3];
  const int wave = tid >> 6;
  if ((tid & 63) == 0) { red[wave][0] = s4; red[wave][1] = s5; red[wave][2] = s6; }
  __syncthreads();
  if (tid == 0) {
    const int bt = b * T_ + t0 + tt;
    out[bt]           = red[0][0] + red[1][0] + red[2][0] + red[3][0] + b4[lab];
    out[BT_ + bt]     = red[0][1] + red[1][1] + red[2][1] + red[3][1] + b5[lab];
    out[2 * BT_ + bt] = red[0][2] + red[1][2] + red[2][2] + red[3][2] + b6[lab];
    if (t0 == 0 && r == 0) { out[3 * BT_] = 0.f; out[3 * BT_ + 1] = 0.f; }
  }
}

__global__ __launch_bounds__(256) void cvt_bf(const float* __restrict__ src,
                                              bf16_t* __restrict__ dst, int n) {
  const int i = (blockIdx.x * 256 + threadIdx.x) * 4;
  if (i + 4 <= n) {
    const float4 v = *(const float4*)&src[i];
    ushort4_t o = {f2bf(v.x), f2bf(v.y), f2bf(v.z), f2bf(v.w)};
    *(ushort4_t*)&dst[i] = o;
  }
}

__global__ __launch_bounds__(256) void zero_h(float* __restrict__ hf,
                                              bf16_t* __restrict__ hb0,
                                              bf16_t* __restrict__ hb1) {
  const int i = blockIdx.x * 256 + threadIdx.x;  // 131072
  hf[i] = 0.f; hb0[i] = 0; hb1[i] = 0;
}

extern "C" void kernel_launch(void* const* d_in, const int* in_sizes, int n_in,
                              void* d_out, int out_size, void* d_ws, size_t ws_size,
                              hipStream_t stream) {
  const float* x     = (const float*)d_in[0];
  const int*   label = (const int*)d_in[1];
  const float* W1    = (const float*)d_in[2];
  const float* b1    = (const float*)d_in[3];
  const float* W2    = (const float*)d_in[4];
  const float* b2    = (const float*)d_in[5];
  const float* W_ih  = (const float*)d_in[6];
  const float* W_hh  = (const float*)d_in[7];
  const float* b_ih  = (const float*)d_in[8];
  const float* b_hh  = (const float*)d_in[9];
  const float* W3    = (const float*)d_in[10];
  const float* b3    = (const float*)d_in[11];
  const float* W4    = (const float*)d_in[12];
  const float* b4    = (const float*)d_in[13];
  const float* W5    = (const float*)d_in[14];
  const float* b5    = (const float*)d_in[15];
  const float* W6    = (const float*)d_in[16];
  const float* b6    = (const float*)d_in[17];

  // Workspace layout (bytes). Base = 98,172,928 (R4-R7 proven).
  // bf16-weight extension (+33,554,432) used only if ws_size permits.
  const size_t NEEDED  = 98172928UL;
  const size_t NEEDED2 = 131727360UL;
  if (ws_size < NEEDED) return;
  const int use_bf = (ws_size >= NEEDED2);

  char* ws = (char*)d_ws;
  bf16_t* xg_c   = (bf16_t*)(ws + 0);
  bf16_t* out2_c = (bf16_t*)(ws + 47972352UL);
  bf16_t* hs_c   = out2_c;
  bf16_t* out1_c = (bf16_t*)(ws + 63963136UL);
  bf16_t* outs_c = out1_c;
  bf16_t* Whh_bf = (bf16_t*)(ws + 71958528UL);
  float*  h_f    = (float*)(ws + 97124352UL);
  bf16_t* hbuf[2];
  hbuf[0] = (bf16_t*)(ws + 97648640UL);
  hbuf[1] = (bf16_t*)(ws + 97910784UL);
  bf16_t* W2b  = (bf16_t*)(ws + 98172928UL);   // 4,194,304 B
  bf16_t* Wihb = (bf16_t*)(ws + 102367232UL);  // 25,165,824 B
  bf16_t* W3b  = (bf16_t*)(ws + 127533056UL);  // 4,194,304 B
  float* out = (float*)d_out;

  const dim3 blk(256);

  cvt_bf<<<dim3(G3_ * HM_ / 1024), blk, 0, stream>>>(W_hh, Whh_bf, G3_ * HM_);
  zero_h<<<dim3(B_ * HM_ / 256), blk, 0, stream>>>(h_f, hbuf[0], hbuf[1]);
  if (use_bf) {
    cvt_bf<<<dim3(H2_ * H1_ / 1024), blk, 0, stream>>>(W2, W2b, H2_ * H1_);
    cvt_bf<<<dim3(G3_ * H2_ / 1024), blk, 0, stream>>>(W_ih, Wihb, G3_ * H2_);
    cvt_bf<<<dim3(PEN_ * HM_ / 1024), blk, 0, stream>>>(W3, W3b, PEN_ * HM_);
  }

  int pp = 0;
  for (int c = 0; c < NCH; ++c) {
    const int t0 = c * TC_;
    gemm_l1_gather<<<dim3(MC / BM, H1_ / BN), blk, 0, stream>>>(x, W1, b1, out1_c, t0);
    if (use_bf) {
      gemm_mfma<1><<<dim3((MC + GBM - 1) / GBM, H2_ / GBN), blk, 0, stream>>>(
          out1_c, nullptr, W2b, b2, out2_c, MC, H2_, H1_, 1);
      gemm_mfma<1><<<dim3((MC + GBM - 1) / GBM, G3_ / GBN), blk, 0, stream>>>(
          out2_c, nullptr, Wihb, b_ih, xg_c, MC, G3_, H2_, 0);
    } else {
      gemm_mfma<0><<<dim3((MC + GBM - 1) / GBM, H2_ / GBN), blk, 0, stream>>>(
          out1_c, W2, nullptr, b2, out2_c, MC, H2_, H1_, 1);
      gemm_mfma<0><<<dim3((MC + GBM - 1) / GBM, G3_ / GBN), blk, 0, stream>>>(
          out2_c, W_ih, nullptr, b_ih, xg_c, MC, G3_, H2_, 0);
    }

    for (int tt = 0; tt < TC_; ++tt) {
      gru_step<<<dim3(HM_ / 16), dim3(512), 0, stream>>>(
          hbuf[pp], h_f, Whh_bf, xg_c, b_hh, hbuf[1 - pp], hs_c, tt);
      pp ^= 1;
    }

    if (use_bf) {
      gemm_mfma<1><<<dim3((MC + GBM - 1) / GBM, PEN_ / GBN), blk, 0, stream>>>(
          hs_c, nullptr, W3b, b3, outs_c, MC, PEN_, HM_, 1);
    } else {
      gemm_mfma<0><<<dim3((MC + GBM - 1) / GBM, PEN_ / GBN), blk, 0, stream>>>(
          hs_c, W3, nullptr, b3, outs_c, MC, PEN_, HM_, 1);
    }
    heads_kernel<<<dim3(MC), blk, 0, stream>>>(
        outs_c, label, W4, b4, W5, b5, W6, b6, out, t0);
  }
}

// Round 6
// 6655.844 us; speedup vs baseline: 1.1528x; 1.0630x over previous
//
#include <hip/hip_runtime.h>
#include <math.h>

#define B_   64
#define T_   366
#define IN_  24
#define H1_  1024
#define H2_  2048
#define HM_  2048
#define G3_  (3 * HM_)
#define PEN_ 1024
#define C_   21
#define BT_  (B_ * T_)

#define TC_  61              // T-chunk length (366 = 6*61)
#define NCH  6
#define MC   (B_ * TC_)      // 3904 rows per chunk

typedef unsigned short bf16_t;
typedef __bf16 bf16x8 __attribute__((ext_vector_type(8)));
typedef float  f32x4  __attribute__((ext_vector_type(4)));

__device__ __forceinline__ float bf2f(bf16_t u) {
  return __uint_as_float(((unsigned int)u) << 16);
}
__device__ __forceinline__ bf16_t f2bf(float f) {
  unsigned int x = __float_as_uint(f);
  unsigned int r = (x + 0x7fffu + ((x >> 16) & 1u)) >> 16;
  return (bf16_t)r;
}

struct ushort4_t { bf16_t x, y, z, w; };

#define AS1 __attribute__((address_space(1)))
#define AS3 __attribute__((address_space(3)))

// ---------------------------------------------------------------------------
// MFMA bf16 GEMM: C = act(A@W^T+b).  (R2-proven, unchanged)
// ---------------------------------------------------------------------------
#define GBM 128
#define GBN 128
#define GBK 32
#define LDT 40

template<int WBF>
__global__ __launch_bounds__(256) void gemm_mfma(
    const bf16_t* __restrict__ A, const float* __restrict__ Wf,
    const bf16_t* __restrict__ Wb,
    const float* __restrict__ bias, bf16_t* __restrict__ C,
    int M, int N, int K, int relu)
{
  __shared__ bf16_t Asl[GBM * LDT];
  __shared__ bf16_t Wsl[GBN * LDT];
  const int tid  = threadIdx.x;
  const int m0   = blockIdx.x * GBM;
  const int n0   = blockIdx.y * GBN;
  const int wave = tid >> 6;
  const int lane = tid & 63;
  const int l16  = lane & 15;
  const int quad = lane >> 4;
  const int wm   = (wave & 1) * 64;
  const int wn   = (wave >> 1) * 64;

  f32x4 acc[4][4];
  #pragma unroll
  for (int i = 0; i < 4; ++i)
    #pragma unroll
    for (int j = 0; j < 4; ++j)
      acc[i][j] = (f32x4){0.f, 0.f, 0.f, 0.f};

  if (WBF) {
    const int r4 = lane >> 2;
    const int sg = (lane & 3) << 3;    // bf16 elems: 0,8,16,24
    for (int k0 = 0; k0 < K; k0 += GBK) {
      #pragma unroll
      for (int it = 0; it < 2; ++it) {
        const int row = wave * 32 + it * 16 + r4;
        const int ar  = (m0 + row < M) ? (m0 + row) : (M - 1);
        __builtin_amdgcn_global_load_lds(
            (const AS1 void*)(A + (size_t)ar * K + k0 + sg),
            (AS3 void*)&Asl[(wave * 2 + it) * 512], 16, 0, 0);
        __builtin_amdgcn_global_load_lds(
            (const AS1 void*)(Wb + (size_t)(n0 + row) * K + k0 + sg),
            (AS3 void*)&Wsl[(wave * 2 + it) * 512], 16, 0, 0);
      }
      __syncthreads();
      bf16x8 af[4], bfr[4];
      #pragma unroll
      for (int i = 0; i < 4; ++i)
        af[i] = *(const bf16x8*)&Asl[(wm + 16 * i + l16) * 32 + quad * 8];
      #pragma unroll
      for (int j = 0; j < 4; ++j)
        bfr[j] = *(const bf16x8*)&Wsl[(wn + 16 * j + l16) * 32 + quad * 8];
      #pragma unroll
      for (int i = 0; i < 4; ++i)
        #pragma unroll
        for (int j = 0; j < 4; ++j)
          acc[i][j] = __builtin_amdgcn_mfma_f32_16x16x32_bf16(af[i], bfr[j], acc[i][j], 0, 0, 0);
      __syncthreads();
    }
  } else {
    const int srow = tid >> 1;
    const int sseg = (tid & 1) << 4;
    const int arow = (m0 + srow < M) ? (m0 + srow) : (M - 1);
    for (int k0 = 0; k0 < K; k0 += GBK) {
      {
        const bf16_t* ga = A + (size_t)arow * K + k0 + sseg;
        const uint4 a0 = *(const uint4*)ga;
        const uint4 a1 = *(const uint4*)(ga + 8);
        *(uint4*)&Asl[srow * LDT + sseg]     = a0;
        *(uint4*)&Asl[srow * LDT + sseg + 8] = a1;
        const float* gw = Wf + (size_t)(n0 + srow) * K + k0 + sseg;
        const float4 w0 = *(const float4*)gw;
        const float4 w1 = *(const float4*)(gw + 4);
        const float4 w2 = *(const float4*)(gw + 8);
        const float4 w3 = *(const float4*)(gw + 12);
        ushort4_t p0 = {f2bf(w0.x), f2bf(w0.y), f2bf(w0.z), f2bf(w0.w)};
        ushort4_t p1 = {f2bf(w1.x), f2bf(w1.y), f2bf(w1.z), f2bf(w1.w)};
        ushort4_t p2 = {f2bf(w2.x), f2bf(w2.y), f2bf(w2.z), f2bf(w2.w)};
        ushort4_t p3 = {f2bf(w3.x), f2bf(w3.y), f2bf(w3.z), f2bf(w3.w)};
        *(ushort4_t*)&Wsl[srow * LDT + sseg]      = p0;
        *(ushort4_t*)&Wsl[srow * LDT + sseg + 4]  = p1;
        *(ushort4_t*)&Wsl[srow * LDT + sseg + 8]  = p2;
        *(ushort4_t*)&Wsl[srow * LDT + sseg + 12] = p3;
      }
      __syncthreads();
      bf16x8 af[4], bfr[4];
      #pragma unroll
      for (int i = 0; i < 4; ++i)
        af[i] = *(const bf16x8*)&Asl[(wm + 16 * i + l16) * LDT + quad * 8];
      #pragma unroll
      for (int j = 0; j < 4; ++j)
        bfr[j] = *(const bf16x8*)&Wsl[(wn + 16 * j + l16) * LDT + quad * 8];
      #pragma unroll
      for (int i = 0; i < 4; ++i)
        #pragma unroll
        for (int j = 0; j < 4; ++j)
          acc[i][j] = __builtin_amdgcn_mfma_f32_16x16x32_bf16(af[i], bfr[j], acc[i][j], 0, 0, 0);
      __syncthreads();
    }
  }

  #pragma unroll
  for (int j = 0; j < 4; ++j) {
    const int n = n0 + wn + 16 * j + l16;
    const float bn = bias[n];
    #pragma unroll
    for (int i = 0; i < 4; ++i) {
      #pragma unroll
      for (int reg = 0; reg < 4; ++reg) {
        const int m = m0 + wm + 16 * i + quad * 4 + reg;
        if (m < M) {
          float v = acc[i][j][reg] + bn;
          if (relu) v = fmaxf(v, 0.f);
          C[(size_t)m * N + n] = f2bf(v);
        }
      }
    }
  }
}

// ---------------------------------------------------------------------------
// GRU step v6 — FULL-CHIP: 256 wgs x 512 thr (all 256 CUs; prior rounds used
// 128 wgs = half chip idle). Each wg owns 8 j-cols. Gate-packed B tiles:
// tile0 rows = [g0 j0..7 | g1 j0..7], tile1 rows = [g2 j0..7 | dup(ignored)].
// K-loop skeleton = R1-proven (2 K-teams, 16 phases, coalesced reg->LDS
// staging, one-ahead prefetch). Epilogue = R2-verified gru_chunk mapping:
// gate sums scattered to sm_g[g][j][b], then one (j,b) pair per thread.
// ---------------------------------------------------------------------------
#define HLD 72   // padded LDS stride for 64-k tiles

__global__ __launch_bounds__(512) void gru_step(
    const bf16_t* __restrict__ h_bf_in, float* __restrict__ h_f,
    const bf16_t* __restrict__ Whh_bf, const bf16_t* __restrict__ xg_c,
    const float* __restrict__ b_hh,
    bf16_t* __restrict__ h_bf_out, bf16_t* __restrict__ hs_c, int tt)
{
  // hst: 2 teams x 64 x HLD x 2B = 18,432 B ; wst: 2 x 24 x HLD x 2B = 6,912 B
  // overlays after K-loop: red (8,192 B on hst) ; sm_g 3x8x64 f32 (6,144 B on wst)
  __shared__ char smem[25344];
  bf16_t* hst = (bf16_t*)smem;
  bf16_t* wst = (bf16_t*)(smem + 18432);
  float*  red = (float*)smem;                // [w4][tile][lane][4] f32 (team1)
  float*  sm_g = (float*)(smem + 18432);     // [g][jj][b] f32

  const int tid  = threadIdx.x;
  const int team = tid >> 8;           // K-half
  const int ttid = tid & 255;
  const int w4   = (tid >> 6) & 3;     // wave within team (= row-tile owner)
  const int lane = tid & 63;
  const int l16  = lane & 15;
  const int quad = lane >> 4;
  const int j0   = blockIdx.x * 8;
  const int kbase = team * (HM_ / 2);

  f32x4 acc0 = (f32x4){0.f, 0.f, 0.f, 0.f};  // tile0: g0 (l16<8) / g1 (l16>=8)
  f32x4 acc1 = acc0;                          // tile1: g2 (l16<8)

  // h staging: 64 rows, 4 thr/row, 32 B each (R1-proven mapping)
  const int hrow = ttid >> 2;
  const int hseg = (ttid & 3) << 4;
  // W staging: 24 rows (g*8+jj), 8 thr/row, 16 B each
  const int wrow = ttid >> 3;          // 0..23 valid for ttid<192
  const int wgi  = wrow >> 3;          // gate
  const int wjr  = wrow & 7;
  const int wseg = (ttid & 7) << 3;    // elems 0..56

  const bf16_t* gh_base = h_bf_in + (size_t)hrow * HM_ + kbase + hseg;
  const bf16_t* gw_base = Whh_bf + (size_t)(wgi * HM_ + j0 + wjr) * HM_ + kbase + wseg;

  // epilogue operand prefetch — ALL 512 threads, one (j,b) pair each
  // (R2-verified gru_chunk mapping)
  const int ej  = tid & 7;
  const int eb  = tid >> 3;            // 0..63
  const int jje = j0 + ej;
  const size_t xrow = (size_t)(eb * TC_ + tt) * G3_;
  const bf16_t xrb = xg_c[xrow + jje];
  const bf16_t xzb = xg_c[xrow + HM_ + jje];
  const bf16_t xnb = xg_c[xrow + 2 * HM_ + jje];
  const float  hp  = h_f[eb * HM_ + jje];
  const float bh_r = b_hh[jje];
  const float bh_z = b_hh[HM_ + jje];
  const float bh_n = b_hh[2 * HM_ + jje];

  // preload k-tile 0
  uint4 h0 = *(const uint4*)(gh_base);
  uint4 h1 = *(const uint4*)(gh_base + 8);
  uint4 w0 = {0u,0u,0u,0u};
  if (ttid < 192) w0 = *(const uint4*)(gw_base);

  bf16_t* hT = hst + team * (64 * HLD);
  bf16_t* wT = wst + team * (24 * HLD);

  for (int k0 = 0; k0 < HM_ / 2; k0 += 64) {
    *(uint4*)&hT[hrow * HLD + hseg]     = h0;
    *(uint4*)&hT[hrow * HLD + hseg + 8] = h1;
    if (ttid < 192) *(uint4*)&wT[wrow * HLD + wseg] = w0;
    __syncthreads();
    if (k0 + 64 < HM_ / 2) {
      h0 = *(const uint4*)(gh_base + k0 + 64);
      h1 = *(const uint4*)(gh_base + k0 + 64 + 8);
      if (ttid < 192) w0 = *(const uint4*)(gw_base + k0 + 64);
    }
    #pragma unroll
    for (int s = 0; s < 2; ++s) {
      const bf16x8 afr = *(const bf16x8*)&hT[(w4 * 16 + l16) * HLD + s * 32 + quad * 8];
      const bf16x8 b0t = *(const bf16x8*)&wT[l16 * HLD + s * 32 + quad * 8];
      const bf16x8 b1t = *(const bf16x8*)&wT[(16 + (l16 & 7)) * HLD + s * 32 + quad * 8];
      acc0 = __builtin_amdgcn_mfma_f32_16x16x32_bf16(afr, b0t, acc0, 0, 0, 0);
      acc1 = __builtin_amdgcn_mfma_f32_16x16x32_bf16(afr, b1t, acc1, 0, 0, 0);
    }
    __syncthreads();
  }

  // team1 -> red (hst overlay; all hst reads complete)
  if (team == 1) {
    *(f32x4*)&red[((w4 * 2 + 0) * 64 + lane) * 4] = acc0;
    *(f32x4*)&red[((w4 * 2 + 1) * 64 + lane) * 4] = acc1;
  }
  __syncthreads();

  // team0: sum + scatter to sm_g[g][jj][b] (wst overlay; wst reads complete)
  if (team == 0) {
    const f32x4 t1a = *(const f32x4*)&red[((w4 * 2 + 0) * 64 + lane) * 4];
    const f32x4 t1b = *(const f32x4*)&red[((w4 * 2 + 1) * 64 + lane) * 4];
    const f32x4 s0 = acc0 + t1a;
    const f32x4 s1 = acc1 + t1b;
    const int ga = (l16 < 8) ? 0 : 1;
    const int jja = l16 & 7;
    #pragma unroll
    for (int reg = 0; reg < 4; ++reg) {
      const int b = w4 * 16 + quad * 4 + reg;
      sm_g[(ga * 8 + jja) * 64 + b] = s0[reg];
      if (l16 < 8) sm_g[(2 * 8 + l16) * 64 + b] = s1[reg];
    }
  }
  __syncthreads();

  // gate math — one (j,b) pair per thread (R2-verified formula/order)
  {
    const float sr = sm_g[(0 * 8 + ej) * 64 + eb];
    const float sz = sm_g[(1 * 8 + ej) * 64 + eb];
    const float sn = sm_g[(2 * 8 + ej) * 64 + eb];
    const float xr = bf2f(xrb), xz = bf2f(xzb), xn = bf2f(xnb);
    const float r = 1.f / (1.f + expf(-(xr + sr + bh_r)));
    const float z = 1.f / (1.f + expf(-(xz + sz + bh_z)));
    const float n = tanhf(xn + r * (sn + bh_n));
    const float hnew = (1.f - z) * n + z * hp;
    h_f[eb * HM_ + jje] = hnew;
    const bf16_t hb = f2bf(hnew);
    h_bf_out[eb * HM_ + jje] = hb;
    hs_c[(size_t)(eb * TC_ + tt) * HM_ + jje] = hb;
  }
}

// ---------------------------------------------------------------------------
// L1 GEMM with gathered rows (K=24, fp32 vector), bf16 output. (R5-proven)
// ---------------------------------------------------------------------------
#define BM 64
#define BN 64
#define BKK 16

__global__ __launch_bounds__(256) void gemm_l1_gather(
    const float* __restrict__ x, const float* __restrict__ W,
    const float* __restrict__ bias, bf16_t* __restrict__ C, int t0)
{
  __shared__ float As[BKK][BM];
  __shared__ float Ws[BKK][BN];
  const int tid = threadIdx.x;
  const int m0 = blockIdx.x * BM;
  const int n0 = blockIdx.y * BN;
  const int lr = tid >> 2;
  const int kq = (tid & 3) << 2;
  const int ty = tid >> 4;
  const int tx = tid & 15;
  const int r = m0 + lr;
  const int b = r / TC_;
  const int tt = r - b * TC_;
  const size_t srow = (size_t)b * T_ + t0 + tt;
  float acc[4][4] = {};
  for (int k0 = 0; k0 < IN_; k0 += BKK) {
    {
      float v0 = 0.f, v1 = 0.f, v2 = 0.f, v3 = 0.f;
      const int kk = k0 + kq;
      const float* src = x + srow * IN_ + kk;
      if (kk + 4 <= IN_) {
        const float4 v = *(const float4*)src;
        v0 = v.x; v1 = v.y; v2 = v.z; v3 = v.w;
      }
      As[kq + 0][lr] = v0; As[kq + 1][lr] = v1;
      As[kq + 2][lr] = v2; As[kq + 3][lr] = v3;
      float w0 = 0.f, w1 = 0.f, w2 = 0.f, w3 = 0.f;
      const float* srcw = W + (size_t)(n0 + lr) * IN_ + kk;
      if (kk + 4 <= IN_) {
        const float4 w = *(const float4*)srcw;
        w0 = w.x; w1 = w.y; w2 = w.z; w3 = w.w;
      }
      Ws[kq + 0][lr] = w0; Ws[kq + 1][lr] = w1;
      Ws[kq + 2][lr] = w2; Ws[kq + 3][lr] = w3;
    }
    __syncthreads();
    #pragma unroll
    for (int k = 0; k < BKK; ++k) {
      const float4 av = *(const float4*)&As[k][ty << 2];
      const float4 bv = *(const float4*)&Ws[k][tx << 2];
      const float aa[4] = {av.x, av.y, av.z, av.w};
      const float bb[4] = {bv.x, bv.y, bv.z, bv.w};
      #pragma unroll
      for (int i = 0; i < 4; ++i)
        #pragma unroll
        for (int j = 0; j < 4; ++j)
          acc[i][j] = fmaf(aa[i], bb[j], acc[i][j]);
    }
    __syncthreads();
  }
  const float4 bvec = *(const float4*)&bias[n0 + (tx << 2)];
  const float bb[4] = {bvec.x, bvec.y, bvec.z, bvec.w};
  #pragma unroll
  for (int i = 0; i < 4; ++i) {
    ushort4_t ov;
    ov.x = f2bf(fmaxf(acc[i][0] + bb[0], 0.f));
    ov.y = f2bf(fmaxf(acc[i][1] + bb[1], 0.f));
    ov.z = f2bf(fmaxf(acc[i][2] + bb[2], 0.f));
    ov.w = f2bf(fmaxf(acc[i][3] + bb[3], 0.f));
    *(ushort4_t*)&C[(size_t)(m0 + (ty << 2) + i) * H1_ + n0 + (tx << 2)] = ov;
  }
}

// Heads for one chunk (outs bf16). (R5-proven)
__global__ __launch_bounds__(256) void heads_kernel(
    const bf16_t* __restrict__ outs_c, const int* __restrict__ label,
    const float* __restrict__ W4, const float* __restrict__ b4,
    const float* __restrict__ W5, const float* __restrict__ b5,
    const float* __restrict__ W6, const float* __restrict__ b6,
    float* __restrict__ out, int t0)
{
  const int r = blockIdx.x;
  const int b = r / TC_;
  const int tt = r - b * TC_;
  int lab = label[b];
  lab = lab < 0 ? 0 : (lab > C_ - 1 ? C_ - 1 : lab);
  const int tid = threadIdx.x;
  const bf16_t* o = outs_c + (size_t)r * PEN_;
  const float* w4 = W4 + (size_t)lab * PEN_;
  const float* w5 = W5 + (size_t)lab * PEN_;
  const float* w6 = W6 + (size_t)lab * PEN_;
  float s4 = 0.f, s5 = 0.f, s6 = 0.f;
  for (int p = tid; p < PEN_; p += 256) {
    const float ov = bf2f(o[p]);
    s4 = fmaf(ov, w4[p], s4);
    s5 = fmaf(ov, w5[p], s5);
    s6 = fmaf(ov, w6[p], s6);
  }
  #pragma unroll
  for (int off = 32; off > 0; off >>= 1) {
    s4 += __shfl_down(s4, off, 64);
    s5 += __shfl_down(s5, off, 64);
    s6 += __shfl_down(s6, off, 64);
  }
  __shared__ float red[4][3];
  const int wave = tid >> 6;
  if ((tid & 63) == 0) { red[wave][0] = s4; red[wave][1] = s5; red[wave][2] = s6; }
  __syncthreads();
  if (tid == 0) {
    const int bt = b * T_ + t0 + tt;
    out[bt]           = red[0][0] + red[1][0] + red[2][0] + red[3][0] + b4[lab];
    out[BT_ + bt]     = red[0][1] + red[1][1] + red[2][1] + red[3][1] + b5[lab];
    out[2 * BT_ + bt] = red[0][2] + red[1][2] + red[2][2] + red[3][2] + b6[lab];
    if (t0 == 0 && r == 0) { out[3 * BT_] = 0.f; out[3 * BT_ + 1] = 0.f; }
  }
}

__global__ __launch_bounds__(256) void cvt_bf(const float* __restrict__ src,
                                              bf16_t* __restrict__ dst, int n) {
  const int i = (blockIdx.x * 256 + threadIdx.x) * 4;
  if (i + 4 <= n) {
    const float4 v = *(const float4*)&src[i];
    ushort4_t o = {f2bf(v.x), f2bf(v.y), f2bf(v.z), f2bf(v.w)};
    *(ushort4_t*)&dst[i] = o;
  }
}

__global__ __launch_bounds__(256) void zero_h(float* __restrict__ hf,
                                              bf16_t* __restrict__ hb0,
                                              bf16_t* __restrict__ hb1) {
  const int i = blockIdx.x * 256 + threadIdx.x;  // 131072
  hf[i] = 0.f; hb0[i] = 0; hb1[i] = 0;
}

extern "C" void kernel_launch(void* const* d_in, const int* in_sizes, int n_in,
                              void* d_out, int out_size, void* d_ws, size_t ws_size,
                              hipStream_t stream) {
  const float* x     = (const float*)d_in[0];
  const int*   label = (const int*)d_in[1];
  const float* W1    = (const float*)d_in[2];
  const float* b1    = (const float*)d_in[3];
  const float* W2    = (const float*)d_in[4];
  const float* b2    = (const float*)d_in[5];
  const float* W_ih  = (const float*)d_in[6];
  const float* W_hh  = (const float*)d_in[7];
  const float* b_ih  = (const float*)d_in[8];
  const float* b_hh  = (const float*)d_in[9];
  const float* W3    = (const float*)d_in[10];
  const float* b3    = (const float*)d_in[11];
  const float* W4    = (const float*)d_in[12];
  const float* b4    = (const float*)d_in[13];
  const float* W5    = (const float*)d_in[14];
  const float* b5    = (const float*)d_in[15];
  const float* W6    = (const float*)d_in[16];
  const float* b6    = (const float*)d_in[17];

  // Workspace layout (bytes). Base = 98,172,928 (R4-R7 proven).
  // bf16-weight extension (+33,554,432) used only if ws_size permits.
  const size_t NEEDED  = 98172928UL;
  const size_t NEEDED2 = 131727360UL;
  if (ws_size < NEEDED) return;
  const int use_bf = (ws_size >= NEEDED2);

  char* ws = (char*)d_ws;
  bf16_t* xg_c   = (bf16_t*)(ws + 0);
  bf16_t* out2_c = (bf16_t*)(ws + 47972352UL);
  bf16_t* hs_c   = out2_c;
  bf16_t* out1_c = (bf16_t*)(ws + 63963136UL);
  bf16_t* outs_c = out1_c;
  bf16_t* Whh_bf = (bf16_t*)(ws + 71958528UL);
  float*  h_f    = (float*)(ws + 97124352UL);
  bf16_t* hbuf[2];
  hbuf[0] = (bf16_t*)(ws + 97648640UL);
  hbuf[1] = (bf16_t*)(ws + 97910784UL);
  bf16_t* W2b  = (bf16_t*)(ws + 98172928UL);   // 4,194,304 B
  bf16_t* Wihb = (bf16_t*)(ws + 102367232UL);  // 25,165,824 B
  bf16_t* W3b  = (bf16_t*)(ws + 127533056UL);  // 4,194,304 B
  float* out = (float*)d_out;

  const dim3 blk(256);

  cvt_bf<<<dim3(G3_ * HM_ / 1024), blk, 0, stream>>>(W_hh, Whh_bf, G3_ * HM_);
  zero_h<<<dim3(B_ * HM_ / 256), blk, 0, stream>>>(h_f, hbuf[0], hbuf[1]);
  if (use_bf) {
    cvt_bf<<<dim3(H2_ * H1_ / 1024), blk, 0, stream>>>(W2, W2b, H2_ * H1_);
    cvt_bf<<<dim3(G3_ * H2_ / 1024), blk, 0, stream>>>(W_ih, Wihb, G3_ * H2_);
    cvt_bf<<<dim3(PEN_ * HM_ / 1024), blk, 0, stream>>>(W3, W3b, PEN_ * HM_);
  }

  int pp = 0;
  for (int c = 0; c < NCH; ++c) {
    const int t0 = c * TC_;
    gemm_l1_gather<<<dim3(MC / BM, H1_ / BN), blk, 0, stream>>>(x, W1, b1, out1_c, t0);
    if (use_bf) {
      gemm_mfma<1><<<dim3((MC + GBM - 1) / GBM, H2_ / GBN), blk, 0, stream>>>(
          out1_c, nullptr, W2b, b2, out2_c, MC, H2_, H1_, 1);
      gemm_mfma<1><<<dim3((MC + GBM - 1) / GBM, G3_ / GBN), blk, 0, stream>>>(
          out2_c, nullptr, Wihb, b_ih, xg_c, MC, G3_, H2_, 0);
    } else {
      gemm_mfma<0><<<dim3((MC + GBM - 1) / GBM, H2_ / GBN), blk, 0, stream>>>(
          out1_c, W2, nullptr, b2, out2_c, MC, H2_, H1_, 1);
      gemm_mfma<0><<<dim3((MC + GBM - 1) / GBM, G3_ / GBN), blk, 0, stream>>>(
          out2_c, W_ih, nullptr, b_ih, xg_c, MC, G3_, H2_, 0);
    }

    for (int tt = 0; tt < TC_; ++tt) {
      gru_step<<<dim3(HM_ / 8), dim3(512), 0, stream>>>(
          hbuf[pp], h_f, Whh_bf, xg_c, b_hh, hbuf[1 - pp], hs_c, tt);
      pp ^= 1;
    }

    if (use_bf) {
      gemm_mfma<1><<<dim3((MC + GBM - 1) / GBM, PEN_ / GBN), blk, 0, stream>>>(
          hs_c, nullptr, W3b, b3, outs_c, MC, PEN_, HM_, 1);
    } else {
      gemm_mfma<0><<<dim3((MC + GBM - 1) / GBM, PEN_ / GBN), blk, 0, stream>>>(
          hs_c, W3, nullptr, b3, outs_c, MC, PEN_, HM_, 1);
    }
    heads_kernel<<<dim3(MC), blk, 0, stream>>>(
        outs_c, label, W4, b4, W5, b5, W6, b6, out, t0);
  }
}